// Round 2
// baseline (466.444 us; speedup 1.0000x reference)
//
#include <hip/hip_runtime.h>
#include <hip/hip_bf16.h>
#include <cstdint>
#include <cstddef>

// Problem constants (reference: BATCH,SEQ,HIDDEN,N_TYPES = 8,1024,256,4; MAX_SPAN=12)
#define BATCH   8
#define SEQLEN  1024
#define HIDDEN  256
#define NSPAN   12222   // 1013*12 + (11+...+1)
#define NFULL   12156   // 1013*12
#define KDIM    512     // 2*HIDDEN
#define NCOL    1024    // NTYPES*HIDDEN
#define NROW    8192    // BATCH*SEQLEN

typedef __bf16 bf16x8 __attribute__((ext_vector_type(8)));
typedef float  f32x4  __attribute__((ext_vector_type(4)));

#define AS1 __attribute__((address_space(1)))
#define AS3 __attribute__((address_space(3)))

__device__ __forceinline__ void load16(const __bf16* g, __bf16* l) {
    // 16B direct global->LDS; LDS dest = wave-uniform base + lane*16 (holds here).
    __builtin_amdgcn_global_load_lds((AS1 const void*)g, (AS3 void*)l, 16, 0, 0);
}

// ---- fp32 -> bf16 conversion (4 elems/thread) ----
__global__ void cvt_bf16(const float* __restrict__ src, __bf16* __restrict__ dst, int n) {
    int i = (blockIdx.x * 256 + threadIdx.x) * 4;
    if (i + 3 < n) {
        float4 f = *(const float4*)(src + i);
        struct alignas(8) B4 { __bf16 a, b, c, d; };
        B4 v;
        v.a = (__bf16)f.x; v.b = (__bf16)f.y; v.c = (__bf16)f.z; v.d = (__bf16)f.w;
        *(B4*)(dst + i) = v;
    }
}

// ---- PQ GEMM:  PQ[half][m][j] = sum_k Hbf[m][k] * Wbf[j][half*256 + k],  k<256
// M=8192 (b*s flat), N=1024, K=256. 128x128 tile, BK=32, 4 waves 2x2.
__global__ __launch_bounds__(256) void pq_gemm(
    const __bf16* __restrict__ Hbf,   // [NROW][HIDDEN]
    const __bf16* __restrict__ Wbf,   // [NCOL][KDIM] (j-major, k contiguous)
    float*        __restrict__ PQ)    // [2][NROW][NCOL]
{
    __shared__ alignas(16) __bf16 As[128 * 32];
    __shared__ alignas(16) __bf16 Bs[128 * 32];

    const int tid  = threadIdx.x;
    const int wave = tid >> 6;
    const int lane = tid & 63;
    const int wm   = (wave >> 1) * 64;
    const int wn   = (wave & 1) * 64;
    const int lr   = lane & 15;
    const int lq   = lane >> 4;

    const int j0   = blockIdx.x * 128;   // col tile (8)
    const int m0   = blockIdx.y * 128;   // row tile (64)
    const int half = blockIdx.z;         // 0=P, 1=Q

    // staging: linear bf16 index l -> row l>>5, col l&31 of the 128x32 tile
    const int l0  = wave * 1024 + lane * 8;
    const int l1  = l0 + 512;
    const int mm0 = l0 >> 5, kk0 = l0 & 31;
    const int mm1 = l1 >> 5, kk1 = l1 & 31;

    const __bf16* a0 = Hbf + (size_t)(m0 + mm0) * HIDDEN + kk0;
    const __bf16* a1 = Hbf + (size_t)(m0 + mm1) * HIDDEN + kk1;
    const __bf16* w0 = Wbf + (size_t)(j0 + mm0) * KDIM + half * HIDDEN + kk0;
    const __bf16* w1 = Wbf + (size_t)(j0 + mm1) * KDIM + half * HIDDEN + kk1;

    f32x4 acc[4][4];
#pragma unroll
    for (int i = 0; i < 4; ++i)
#pragma unroll
        for (int j = 0; j < 4; ++j)
            acc[i][j] = (f32x4){0.f, 0.f, 0.f, 0.f};

    for (int ks = 0; ks < 8; ++ks) {
        const int c0 = ks * 32;
        __syncthreads();
        load16(a0 + c0, &As[l0]);
        load16(a1 + c0, &As[l1]);
        load16(w0 + c0, &Bs[l0]);
        load16(w1 + c0, &Bs[l1]);
        __syncthreads();

        bf16x8 af[4], bfv[4];
#pragma unroll
        for (int mi = 0; mi < 4; ++mi)
            af[mi] = *(const bf16x8*)(As + (wm + mi * 16 + lr) * 32 + lq * 8);
#pragma unroll
        for (int ni = 0; ni < 4; ++ni)
            bfv[ni] = *(const bf16x8*)(Bs + (wn + ni * 16 + lr) * 32 + lq * 8);
#pragma unroll
        for (int mi = 0; mi < 4; ++mi)
#pragma unroll
            for (int ni = 0; ni < 4; ++ni)
                acc[mi][ni] = __builtin_amdgcn_mfma_f32_16x16x32_bf16(
                    af[mi], bfv[ni], acc[mi][ni], 0, 0, 0);
    }

    float* base = PQ + (size_t)half * NROW * NCOL;
#pragma unroll
    for (int mi = 0; mi < 4; ++mi) {
#pragma unroll
        for (int r = 0; r < 4; ++r) {
            const int m = m0 + wm + mi * 16 + lq * 4 + r;   // C/D: row = quad*4+reg
            float* op = base + (size_t)m * NCOL + (j0 + wn + lr);
#pragma unroll
            for (int ni = 0; ni < 4; ++ni)
                op[ni * 16] = acc[mi][ni][r];
        }
    }
}

// ---- assembly: out[b][n][j] = P[b][s(n)][j] + Q[b][e(n)][j] + bias[j] ----
// 4 span-rows per block, 256 threads x float4 covers the 1024 columns.
__global__ __launch_bounds__(256) void span_add(
    const float* __restrict__ PQ,     // [2][NROW][NCOL]
    const float* __restrict__ bias,   // [NCOL]
    float*       __restrict__ out)    // [BATCH][NSPAN][NCOL]
{
    const int b  = blockIdx.y;
    const int n0 = blockIdx.x * 4;
    const int j  = threadIdx.x * 4;

    const float4 bv = *(const float4*)(bias + j);
    const float* Pb = PQ + (size_t)b * SEQLEN * NCOL;
    const float* Qb = Pb + (size_t)NROW * NCOL;
    float* ob = out + (size_t)b * NSPAN * NCOL;

#pragma unroll
    for (int r = 0; r < 4; ++r) {
        const int n = n0 + r;
        if (n >= NSPAN) break;
        int s, e;
        if (n < NFULL) {
            s = n / 12;
            e = s + (n - s * 12);
        } else {
            int rr = n - NFULL;
            s = SEQLEN - 11;
            int cnt = 11;
            while (rr >= cnt) { rr -= cnt; --cnt; ++s; }
            e = s + rr;
        }
        const float4 p = *(const float4*)(Pb + (size_t)s * NCOL + j);
        const float4 q = *(const float4*)(Qb + (size_t)e * NCOL + j);
        float4 o;
        o.x = p.x + q.x + bv.x;
        o.y = p.y + q.y + bv.y;
        o.z = p.z + q.z + bv.z;
        o.w = p.w + q.w + bv.w;
        *(float4*)(ob + (size_t)n * NCOL + j) = o;
    }
}

extern "C" void kernel_launch(void* const* d_in, const int* in_sizes, int n_in,
                              void* d_out, int out_size, void* d_ws, size_t ws_size,
                              hipStream_t stream) {
    const float* hid  = (const float*)d_in[0];   // [8,1024,256]
    const float* W    = (const float*)d_in[1];   // [4,256,512]
    const float* bias = (const float*)d_in[2];   // [4,256] flat [1024]
    float* out = (float*)d_out;

    // ws layout: Wbf (1 MB) | Hbf (4 MB) | PQ fp32 (64 MB)
    char* ws = (char*)d_ws;
    __bf16* Wbf = (__bf16*)ws;
    __bf16* Hbf = (__bf16*)(ws + (size_t)1048576);
    float*  PQ  = (float*)(ws + (size_t)(1048576 + 4194304));

    cvt_bf16<<<512,  256, 0, stream>>>(W,   Wbf, NCOL * KDIM);
    cvt_bf16<<<2048, 256, 0, stream>>>(hid, Hbf, NROW * HIDDEN);
    pq_gemm<<<dim3(8, 64, 2), 256, 0, stream>>>(Hbf, Wbf, PQ);
    span_add<<<dim3((NSPAN + 3) / 4, BATCH), 256, 0, stream>>>(PQ, bias, out);
}